// Round 7
// baseline (1160.184 us; speedup 1.0000x reference)
//
#include <hip/hip_runtime.h>

// ---------------------------------------------------------------------------
// 3-layer GCN (PyG gcn_norm semantics) on MI355X.
// THIS ROUND: measurement build. gemm1 repeats its full pipeline 5x
// (identical work, deterministic) so its dispatch exceeds the ~650us
// harness fillBuffer rows and surfaces in rocprof top-5 WITH counters.
// Everything else is exactly the best-known config (R5, 416us).
//   0. init: zero cnt + detect edge_index storage (int32 vs int64)
//   1. degree count ; scan -> CSR offsets (+dis, +cursor=0) ; fill CSR
//   2. W1 -> split bf16 hi/lo + transpose (Bt[2][64][K])
//   3. H0 = x @ W1 split-bf16 MFMA, K-split x4, NT A-loads, XCD swizzle
//   4. H1 = relu(Agg(H0)+b1) ; H2 = relu(Agg(H1@W2)+b2)
//   5. out = softmax(Agg(H2@W3)+b3)
// ---------------------------------------------------------------------------

#define GEMM1_REPS 5  // MEASUREMENT: revert to 1 after reading counters

typedef __attribute__((ext_vector_type(8))) short bf16x8;
typedef __attribute__((ext_vector_type(4))) float f32x4;
typedef __attribute__((ext_vector_type(4))) float fv4;

__device__ __forceinline__ float4 ldnt4(const float* p) {
    fv4 v = __builtin_nontemporal_load((const fv4*)p);
    return make_float4(v.x, v.y, v.z, v.w);
}
__device__ __forceinline__ void stnt(float* p, float v) {
    __builtin_nontemporal_store(v, p);
}

__device__ __forceinline__ unsigned cvt_pk_bf16(float a, float b) {
    // D[15:0] = bf16_rne(a), D[31:16] = bf16_rne(b)
    unsigned r;
    asm("v_cvt_pk_bf16_f32 %0, %1, %2" : "=v"(r) : "v"(a), "v"(b));
    return r;
}

__device__ __forceinline__ unsigned short f2bf_rne(float f) {
    unsigned u = __float_as_uint(f);
    unsigned r = (u + 0x7FFFu + ((u >> 16) & 1u)) >> 16;
    return (unsigned short)r;
}

// --- zero cnt; thread 0 probes int64-vs-int32 (int64 < 2^31 -> odd words 0)
__global__ void init_k(const int* __restrict__ ei, int* __restrict__ flag,
                       int* __restrict__ cnt, int n) {
    int t = blockIdx.x * blockDim.x + threadIdx.x;
    if (t < n) cnt[t] = 0;
    if (t == 0) {
        int f = 1;
        for (int i = 0; i < 256; ++i) {
            if (ei[2 * i + 1] != 0) { f = 0; break; }
        }
        *flag = f;
    }
}

__device__ __forceinline__ int edge_val(const int* __restrict__ ei, long long idx, int f64) {
    return f64 ? ei[2 * idx] : ei[(int)idx];
}

__global__ void count_deg_k(const int* __restrict__ ei, int E, const int* __restrict__ flag,
                            int* __restrict__ cnt) {
    int e = blockIdx.x * blockDim.x + threadIdx.x;
    if (e >= E) return;
    int f = *flag;
    int c = edge_val(ei, (long long)E + e, f);
    atomicAdd(&cnt[c], 1);
}

// scan + dis + cursor init, single block
__global__ void scan_k(const int* __restrict__ cnt, int* __restrict__ offs,
                       float* __restrict__ dis, int* __restrict__ cursor, int n) {
    __shared__ int sums[1024];
    const int t = threadIdx.x;
    const int base = t * 16;
    int loc[16];
    int s = 0;
#pragma unroll
    for (int i = 0; i < 16; ++i) {
        loc[i] = s;
        int idx = base + i;
        s += (idx < n) ? cnt[idx] : 0;
    }
    sums[t] = s;
    __syncthreads();
    for (int o = 1; o < 1024; o <<= 1) {
        int v = (t >= o) ? sums[t - o] : 0;
        __syncthreads();
        sums[t] += v;
        __syncthreads();
    }
    int tbase = (t == 0) ? 0 : sums[t - 1];
#pragma unroll
    for (int i = 0; i < 16; ++i) {
        int idx = base + i;
        if (idx < n) {
            offs[idx] = tbase + loc[i];
            cursor[idx] = 0;
            dis[idx] = rsqrtf((float)(cnt[idx] + 1));  // +1: self loop
        }
    }
    if (t == 1023) offs[n] = sums[1023];
}

__global__ void fill_csr_k(const int* __restrict__ ei, int E, const int* __restrict__ flag,
                           const int* __restrict__ offs, int* __restrict__ cursor,
                           const float* __restrict__ dis, int* __restrict__ src,
                           float* __restrict__ w) {
    int e = blockIdx.x * blockDim.x + threadIdx.x;
    if (e >= E) return;
    int f = *flag;
    int r = edge_val(ei, (long long)e, f);
    int c = edge_val(ei, (long long)E + e, f);
    int pos = offs[c] + atomicAdd(&cursor[c], 1);
    src[pos] = r;
    w[pos] = dis[r] * dis[c];
}

// --- W1 [K][64] fp32 -> Bt[2][64][K] bf16 (hi, lo), transposed.
__global__ void prep_w1_k(const float* __restrict__ W1, unsigned short* __restrict__ Bt,
                          int K) {
    int g = blockIdx.x * blockDim.x + threadIdx.x;
    if (g >= K * 64) return;
    int nn = g & 63, k = g >> 6;
    float f = W1[(size_t)k * 64 + nn];
    unsigned short hi = f2bf_rne(f);
    float hf = __uint_as_float((unsigned)hi << 16);
    unsigned short lo = f2bf_rne(f - hf);
    Bt[(size_t)nn * K + k] = hi;
    Bt[(size_t)64 * K + (size_t)nn * K + k] = lo;
}

// --- GEMM1: [n x K] fp32 @ Bt[2][64][K] -> P[kz][n][64], split-bf16 MFMA.
// BM=128, BN=64, BK=32, 256 thr = 4 waves (2m x 2n), wave tile 64x32.
// K-split x4. A loads NT, B loads cached. GEMM1_REPS outer reps (measurement).
__global__ __launch_bounds__(256) void gemm1_mfma_k(
    const float* __restrict__ A, const unsigned short* __restrict__ Bt,
    float* __restrict__ P, int n, int K, int kchunk) {
    __shared__ unsigned short As[2][128][40];  // [hi/lo][row][k], pad 40
    const int tid = threadIdx.x;
    const int lane = tid & 63;
    const int wid = tid >> 6;
    const int wm = wid >> 1, wn = wid & 1;
    const int lrow = lane & 15, lkh = lane >> 4;
    // XCD-grouped swizzle: XCD pair {2y,2y+1} owns K-chunk y -> its 2MB of B
    const int bid = blockIdx.x;
    const int by = (bid & 7) >> 1;
    const int bx = ((bid >> 3) << 1) | (bid & 1);
    const int bm = bx * 128;
    const int k0 = by * kchunk;
    const int iters = kchunk / 32;  // K=16384 /4 /32 = 128

    const unsigned short* Bh = Bt;
    const unsigned short* Bl = Bt + (size_t)64 * K;

    f32x4 acc[4][2];
    float4 st[4];

    auto loadA = [&](int kt) {
#pragma unroll
        for (int i = 0; i < 4; ++i) {
            int v = tid + i * 256;
            int r = v >> 3, c = (v & 7) * 4;
            st[i] = ldnt4(A + (size_t)(bm + r) * K + k0 + kt * 32 + c);
        }
    };

    const f32x4 zero = {0.f, 0.f, 0.f, 0.f};
    for (int rep = 0; rep < GEMM1_REPS; ++rep) {
#pragma unroll
        for (int mf = 0; mf < 4; ++mf)
#pragma unroll
            for (int nf = 0; nf < 2; ++nf) acc[mf][nf] = zero;

        loadA(0);
        for (int kt = 0; kt < iters; ++kt) {
            // B fragments from global (L2-resident; NOT nt)
            bf16x8 bh[2], bl[2];
#pragma unroll
            for (int nf = 0; nf < 2; ++nf) {
                int brow = wn * 32 + nf * 16 + lrow;
                size_t bo = (size_t)brow * K + k0 + kt * 32 + lkh * 8;
                bh[nf] = *(const bf16x8*)(Bh + bo);
                bl[nf] = *(const bf16x8*)(Bl + bo);
            }
            // convert staged A regs -> hi/lo bf16 -> LDS
#pragma unroll
            for (int i = 0; i < 4; ++i) {
                int v = tid + i * 256;
                int r = v >> 3, c = (v & 7) * 4;
                float f0 = st[i].x, f1 = st[i].y, f2 = st[i].z, f3 = st[i].w;
                unsigned h01 = cvt_pk_bf16(f0, f1);
                unsigned h23 = cvt_pk_bf16(f2, f3);
                float r0 = f0 - __uint_as_float(h01 << 16);
                float r1 = f1 - __uint_as_float(h01 & 0xFFFF0000u);
                float r2 = f2 - __uint_as_float(h23 << 16);
                float r3 = f3 - __uint_as_float(h23 & 0xFFFF0000u);
                unsigned l01 = cvt_pk_bf16(r0, r1);
                unsigned l23 = cvt_pk_bf16(r2, r3);
                *(uint2*)&As[0][r][c] = make_uint2(h01, h23);
                *(uint2*)&As[1][r][c] = make_uint2(l01, l23);
            }
            __syncthreads();
            if (kt + 1 < iters) loadA(kt + 1);  // prefetch under MFMA
            bf16x8 ah[4], al[4];
#pragma unroll
            for (int mf = 0; mf < 4; ++mf) {
                int row = wm * 64 + mf * 16 + lrow;
                ah[mf] = *(const bf16x8*)&As[0][row][lkh * 8];
                al[mf] = *(const bf16x8*)&As[1][row][lkh * 8];
            }
#pragma unroll
            for (int mf = 0; mf < 4; ++mf)
#pragma unroll
                for (int nf = 0; nf < 2; ++nf) {
                    acc[mf][nf] = __builtin_amdgcn_mfma_f32_16x16x32_bf16(ah[mf], bh[nf], acc[mf][nf], 0, 0, 0);
                    acc[mf][nf] = __builtin_amdgcn_mfma_f32_16x16x32_bf16(al[mf], bh[nf], acc[mf][nf], 0, 0, 0);
                    acc[mf][nf] = __builtin_amdgcn_mfma_f32_16x16x32_bf16(ah[mf], bl[nf], acc[mf][nf], 0, 0, 0);
                }
            __syncthreads();
        }
    }

    // C/D layout: col = lane&15, row = (lane>>4)*4 + reg. NT stores (read once).
    float* out = P + (size_t)by * n * 64;
#pragma unroll
    for (int mf = 0; mf < 4; ++mf)
#pragma unroll
        for (int nf = 0; nf < 2; ++nf)
#pragma unroll
            for (int j = 0; j < 4; ++j) {
                int row = bm + wm * 64 + mf * 16 + lkh * 4 + j;
                int col = wn * 32 + nf * 16 + lrow;
                stnt(out + (size_t)row * 64 + col, acc[mf][nf][j]);
            }
}

__global__ void reduce4_k(float4* __restrict__ p, size_t q) {
    size_t i = (size_t)blockIdx.x * blockDim.x + threadIdx.x;
    if (i >= q) return;
    float4 a = p[i];
#pragma unroll
    for (int z = 1; z < 4; ++z) {
        float4 b = ldnt4((const float*)(p + i + (size_t)z * q));
        a.x += b.x; a.y += b.y; a.z += b.z; a.w += b.w;
    }
    p[i] = a;
}

// --- propagate, float4 per thread: out[i,:] = sum_e w_e*h[src_e,:] + dis^2*h[i,:] + b
template <int F, bool RELU>
__global__ void prop_k(const float* __restrict__ h, const int* __restrict__ offs,
                       const int* __restrict__ src, const float* __restrict__ w,
                       const float* __restrict__ dis, const float* __restrict__ b,
                       float* __restrict__ out, int n) {
    constexpr int LPN = F / 4;
    int t = blockIdx.x * blockDim.x + threadIdx.x;
    int node = t / LPN, q = t % LPN;
    if (node >= n) return;
    float4 acc = make_float4(0.f, 0.f, 0.f, 0.f);
    int p0 = offs[node], p1 = offs[node + 1];
    for (int p = p0; p < p1; ++p) {
        float ww = w[p];
        float4 hv = *(const float4*)(h + (size_t)src[p] * F + q * 4);
        acc.x = fmaf(ww, hv.x, acc.x);
        acc.y = fmaf(ww, hv.y, acc.y);
        acc.z = fmaf(ww, hv.z, acc.z);
        acc.w = fmaf(ww, hv.w, acc.w);
    }
    float d = dis[node];
    float ds = d * d;
    float4 hv = *(const float4*)(h + (size_t)node * F + q * 4);
    float4 bv = *(const float4*)(b + q * 4);
    acc.x = fmaf(ds, hv.x, acc.x) + bv.x;
    acc.y = fmaf(ds, hv.y, acc.y) + bv.y;
    acc.z = fmaf(ds, hv.z, acc.z) + bv.z;
    acc.w = fmaf(ds, hv.w, acc.w) + bv.w;
    if (RELU) {
        acc.x = fmaxf(acc.x, 0.f);
        acc.y = fmaxf(acc.y, 0.f);
        acc.z = fmaxf(acc.z, 0.f);
        acc.w = fmaxf(acc.w, 0.f);
    }
    *(float4*)(out + (size_t)node * F + q * 4) = acc;
}

template <int K, int FO>
__global__ void gemm_small_k(const float* __restrict__ h, const float* __restrict__ W,
                             float* __restrict__ out, int n) {
    __shared__ float Ws[K * FO];
    for (int i = threadIdx.x; i < K * FO; i += blockDim.x) Ws[i] = W[i];
    __syncthreads();
    int t = blockIdx.x * blockDim.x + threadIdx.x;
    int node = t / FO, c = t % FO;
    if (node >= n) return;
    const float4* h4 = (const float4*)(h + (size_t)node * K);
    float acc = 0.f;
#pragma unroll
    for (int k4 = 0; k4 < K / 4; ++k4) {
        float4 v = h4[k4];
        acc = fmaf(v.x, Ws[(k4 * 4 + 0) * FO + c], acc);
        acc = fmaf(v.y, Ws[(k4 * 4 + 1) * FO + c], acc);
        acc = fmaf(v.z, Ws[(k4 * 4 + 2) * FO + c], acc);
        acc = fmaf(v.w, Ws[(k4 * 4 + 3) * FO + c], acc);
    }
    out[t] = acc;
}

// --- final propagate (F=16) + bias + softmax, float4/thread, 4 lanes/node
__global__ void prop_softmax_k(const float* __restrict__ h, const int* __restrict__ offs,
                               const int* __restrict__ src, const float* __restrict__ w,
                               const float* __restrict__ dis, const float* __restrict__ b,
                               float* __restrict__ out, int n) {
    int t = blockIdx.x * blockDim.x + threadIdx.x;
    int node = t >> 2, q = t & 3;
    if (node >= n) return;
    float4 acc = make_float4(0.f, 0.f, 0.f, 0.f);
    int p0 = offs[node], p1 = offs[node + 1];
    for (int p = p0; p < p1; ++p) {
        float ww = w[p];
        float4 hv = *(const float4*)(h + (size_t)src[p] * 16 + q * 4);
        acc.x = fmaf(ww, hv.x, acc.x);
        acc.y = fmaf(ww, hv.y, acc.y);
        acc.z = fmaf(ww, hv.z, acc.z);
        acc.w = fmaf(ww, hv.w, acc.w);
    }
    float d = dis[node];
    float ds = d * d;
    float4 hv = *(const float4*)(h + (size_t)node * 16 + q * 4);
    float4 bv = *(const float4*)(b + q * 4);
    acc.x = fmaf(ds, hv.x, acc.x) + bv.x;
    acc.y = fmaf(ds, hv.y, acc.y) + bv.y;
    acc.z = fmaf(ds, hv.z, acc.z) + bv.z;
    acc.w = fmaf(ds, hv.w, acc.w) + bv.w;
    float m = fmaxf(fmaxf(acc.x, acc.y), fmaxf(acc.z, acc.w));
    m = fmaxf(m, __shfl_xor(m, 1));
    m = fmaxf(m, __shfl_xor(m, 2));
    float4 e;
    e.x = __expf(acc.x - m);
    e.y = __expf(acc.y - m);
    e.z = __expf(acc.z - m);
    e.w = __expf(acc.w - m);
    float s = e.x + e.y + e.z + e.w;
    s += __shfl_xor(s, 1);
    s += __shfl_xor(s, 2);
    float inv = 1.f / s;
    e.x *= inv; e.y *= inv; e.z *= inv; e.w *= inv;
    *(float4*)(out + (size_t)node * 16 + q * 4) = e;
}

extern "C" void kernel_launch(void* const* d_in, const int* in_sizes, int n_in,
                              void* d_out, int out_size, void* d_ws, size_t ws_size,
                              hipStream_t stream) {
    const float* x  = (const float*)d_in[0];
    const int*   ei = (const int*)d_in[1];
    const float* W1 = (const float*)d_in[2];
    const float* b1 = (const float*)d_in[3];
    const float* W2 = (const float*)d_in[4];
    const float* b2 = (const float*)d_in[5];
    const float* W3 = (const float*)d_in[6];
    const float* b3 = (const float*)d_in[7];
    float* out = (float*)d_out;

    const int n = in_sizes[2] / 64;
    const int K = in_sizes[0] / n;
    const int E = in_sizes[1] / 2;

    char* ws = (char*)d_ws;
    size_t off = 0;
    auto alloc = [&](size_t bytes) {
        char* p = ws + off;
        off = (off + bytes + 255) & ~(size_t)255;
        return p;
    };
    int*   flag   = (int*)  alloc(4);
    int*   cnt    = (int*)  alloc((size_t)n * 4);
    int*   cursor = (int*)  alloc((size_t)n * 4);
    int*   offs   = (int*)  alloc((size_t)(n + 1) * 4);
    float* dis    = (float*)alloc((size_t)n * 4);
    int*   csrs   = (int*)  alloc((size_t)E * 4);
    float* csrw   = (float*)alloc((size_t)E * 4);
    unsigned short* Btw = (unsigned short*)alloc((size_t)2 * 64 * K * 2);
    float* P      = (float*)alloc((size_t)4 * n * 64 * 4);  // partials; plane 0 = H0
    float* H1     = (float*)alloc((size_t)n * 64 * 4);
    float* H2a    = (float*)alloc((size_t)n * 32 * 4);
    float* H2     = (float*)alloc((size_t)n * 32 * 4);
    float* H3a    = (float*)alloc((size_t)n * 16 * 4);
    (void)ws_size; (void)n_in; (void)out_size;

    init_k<<<(n + 255) / 256, 256, 0, stream>>>(ei, flag, cnt, n);
    count_deg_k<<<(E + 255) / 256, 256, 0, stream>>>(ei, E, flag, cnt);
    scan_k<<<1, 1024, 0, stream>>>(cnt, offs, dis, cursor, n);
    fill_csr_k<<<(E + 255) / 256, 256, 0, stream>>>(ei, E, flag, offs, cursor, dis, csrs, csrw);
    prep_w1_k<<<(K * 64 + 255) / 256, 256, 0, stream>>>(W1, Btw, K);

    gemm1_mfma_k<<<(n / 128) * 4, 256, 0, stream>>>(x, Btw, P, n, K, K / 4);
    size_t q = (size_t)n * 64 / 4;
    reduce4_k<<<(int)((q + 255) / 256), 256, 0, stream>>>((float4*)P, q);

    prop_k<64, true><<<(n * 16 + 255) / 256, 256, 0, stream>>>(P, offs, csrs, csrw, dis, b1, H1, n);
    gemm_small_k<64, 32><<<(n * 32 + 255) / 256, 256, 0, stream>>>(H1, W2, H2a, n);
    prop_k<32, true><<<(n * 8 + 255) / 256, 256, 0, stream>>>(H2a, offs, csrs, csrw, dis, b2, H2, n);
    gemm_small_k<32, 16><<<(n * 16 + 255) / 256, 256, 0, stream>>>(H2, W3, H3a, n);
    prop_softmax_k<<<(n * 4 + 255) / 256, 256, 0, stream>>>(H3a, offs, csrs, csrw, dis, b3, out, n);
}

// Round 8
// 478.991 us; speedup vs baseline: 2.4221x; 2.4221x over previous
//
#include <hip/hip_runtime.h>

// ---------------------------------------------------------------------------
// 3-layer GCN (PyG gcn_norm semantics) on MI355X.
//   0. init: zero cnt + detect edge_index storage (int32 vs int64)
//   1. degree count ; scan -> CSR offsets (+dis, +cursor=0) ; fill CSR
//   2. W1 -> split bf16 hi/lo + transpose (Bt[2][64][K])
//   3. H0 = x @ W1 split-bf16 MFMA (xh*Wh + xl*Wh + xh*Wl), K-split x8.
//      m97 2-phase: fp32 A tile staged via global_load_lds (DMA, no VGPR
//      round-trip), double-buffered; STAGE(next) issued BEFORE compute so
//      the single __syncthreads drain per K-step is covered by compute.
//      LDS XOR-swizzle (16B slot ^= row&7) applied on the pre-swizzled
//      GLOBAL source + swizzled ds_read (rule #21). Convert on consumer
//      side via v_cvt_pk_bf16_f32. Grid 1024 (4 blocks/CU), XCD-grouped.
//   4. H1 = relu(Agg(H0)+b1) ; H2 = relu(Agg(H1@W2)+b2)
//   5. out = softmax(Agg(H2@W3)+b3)
// ---------------------------------------------------------------------------

typedef __attribute__((ext_vector_type(8))) short bf16x8;
typedef __attribute__((ext_vector_type(4))) float f32x4;
typedef __attribute__((ext_vector_type(4))) float fv4;

union PK4 { unsigned u[4]; bf16x8 v; };

__device__ __forceinline__ float4 ldnt4(const float* p) {
    fv4 v = __builtin_nontemporal_load((const fv4*)p);
    return make_float4(v.x, v.y, v.z, v.w);
}
__device__ __forceinline__ void stnt(float* p, float v) {
    __builtin_nontemporal_store(v, p);
}

__device__ __forceinline__ unsigned cvt_pk_bf16(float a, float b) {
    // D[15:0] = bf16_rne(a), D[31:16] = bf16_rne(b)
    unsigned r;
    asm("v_cvt_pk_bf16_f32 %0, %1, %2" : "=v"(r) : "v"(a), "v"(b));
    return r;
}

// async global->LDS DMA, 16B per lane; lds dest = wave-uniform base + lane*16
__device__ __forceinline__ void gload_lds16(const float* g, void* lds) {
    __builtin_amdgcn_global_load_lds(
        (const __attribute__((address_space(1))) unsigned*)g,
        (__attribute__((address_space(3))) unsigned*)lds, 16, 0, 0);
}

__device__ __forceinline__ unsigned short f2bf_rne(float f) {
    unsigned u = __float_as_uint(f);
    unsigned r = (u + 0x7FFFu + ((u >> 16) & 1u)) >> 16;
    return (unsigned short)r;
}

// --- zero cnt; thread 0 probes int64-vs-int32 (int64 < 2^31 -> odd words 0)
__global__ void init_k(const int* __restrict__ ei, int* __restrict__ flag,
                       int* __restrict__ cnt, int n) {
    int t = blockIdx.x * blockDim.x + threadIdx.x;
    if (t < n) cnt[t] = 0;
    if (t == 0) {
        int f = 1;
        for (int i = 0; i < 256; ++i) {
            if (ei[2 * i + 1] != 0) { f = 0; break; }
        }
        *flag = f;
    }
}

__device__ __forceinline__ int edge_val(const int* __restrict__ ei, long long idx, int f64) {
    return f64 ? ei[2 * idx] : ei[(int)idx];
}

__global__ void count_deg_k(const int* __restrict__ ei, int E, const int* __restrict__ flag,
                            int* __restrict__ cnt) {
    int e = blockIdx.x * blockDim.x + threadIdx.x;
    if (e >= E) return;
    int f = *flag;
    int c = edge_val(ei, (long long)E + e, f);
    atomicAdd(&cnt[c], 1);
}

// scan + dis + cursor init, single block
__global__ void scan_k(const int* __restrict__ cnt, int* __restrict__ offs,
                       float* __restrict__ dis, int* __restrict__ cursor, int n) {
    __shared__ int sums[1024];
    const int t = threadIdx.x;
    const int base = t * 16;
    int loc[16];
    int s = 0;
#pragma unroll
    for (int i = 0; i < 16; ++i) {
        loc[i] = s;
        int idx = base + i;
        s += (idx < n) ? cnt[idx] : 0;
    }
    sums[t] = s;
    __syncthreads();
    for (int o = 1; o < 1024; o <<= 1) {
        int v = (t >= o) ? sums[t - o] : 0;
        __syncthreads();
        sums[t] += v;
        __syncthreads();
    }
    int tbase = (t == 0) ? 0 : sums[t - 1];
#pragma unroll
    for (int i = 0; i < 16; ++i) {
        int idx = base + i;
        if (idx < n) {
            offs[idx] = tbase + loc[i];
            cursor[idx] = 0;
            dis[idx] = rsqrtf((float)(cnt[idx] + 1));  // +1: self loop
        }
    }
    if (t == 1023) offs[n] = sums[1023];
}

__global__ void fill_csr_k(const int* __restrict__ ei, int E, const int* __restrict__ flag,
                           const int* __restrict__ offs, int* __restrict__ cursor,
                           const float* __restrict__ dis, int* __restrict__ src,
                           float* __restrict__ w) {
    int e = blockIdx.x * blockDim.x + threadIdx.x;
    if (e >= E) return;
    int f = *flag;
    int r = edge_val(ei, (long long)e, f);
    int c = edge_val(ei, (long long)E + e, f);
    int pos = offs[c] + atomicAdd(&cursor[c], 1);
    src[pos] = r;
    w[pos] = dis[r] * dis[c];
}

// --- W1 [K][64] fp32 -> Bt[2][64][K] bf16 (hi, lo), transposed.
__global__ void prep_w1_k(const float* __restrict__ W1, unsigned short* __restrict__ Bt,
                          int K) {
    int g = blockIdx.x * blockDim.x + threadIdx.x;
    if (g >= K * 64) return;
    int nn = g & 63, k = g >> 6;
    float f = W1[(size_t)k * 64 + nn];
    unsigned short hi = f2bf_rne(f);
    float hf = __uint_as_float((unsigned)hi << 16);
    unsigned short lo = f2bf_rne(f - hf);
    Bt[(size_t)nn * K + k] = hi;
    Bt[(size_t)64 * K + (size_t)nn * K + k] = lo;
}

// --- GEMM1: [n x K] fp32 @ Bt[2][64][K] -> P[kz][n][64], split-bf16 MFMA.
// BM=128, BN=64, BK=32, 256 thr = 4 waves (2m x 2n), wave tile 64x32.
// K-split x8 (grid 1024 = 4 blocks/CU). A: global_load_lds double-buffer.
__global__ __launch_bounds__(256) void gemm1_mfma_k(
    const float* __restrict__ A, const unsigned short* __restrict__ Bt,
    float* __restrict__ P, int n, int K, int kchunk) {
    __shared__ float As[2][128][32];  // linear; data swizzled (slot ^= row&7)
    const int tid = threadIdx.x;
    const int lane = tid & 63;
    const int wid = tid >> 6;
    const int wm = wid >> 1, wn = wid & 1;
    const int lrow = lane & 15, lkh = lane >> 4;
    // XCD grouping: by = bid&7 -> XCD i (round-robin dispatch) sees one
    // 512KB B-chunk only; bx covers rows.
    const int bid = blockIdx.x;
    const int by = bid & 7;
    const int bx = bid >> 3;
    const int bm = bx * 128;
    const int k0 = by * kchunk;
    const int iters = kchunk / 32;  // K=16384 /8 /32 = 64

    const unsigned short* Bh = Bt;
    const unsigned short* Bl = Bt + (size_t)64 * K;

    f32x4 acc[4][2] = {};

    // stage fp32 tile [128][32] for K-step kt into As[buf] via DMA.
    // slot g (16B) = ch*256+tid; LDS linear; source col-group pre-swizzled:
    // LDS slot (row, sl) receives data cols 4*(sl^(row&7))..+3.
    auto stage = [&](int buf, int kt) {
        const float* base = A + (size_t)bm * K + k0 + kt * 32;
#pragma unroll
        for (int ch = 0; ch < 4; ++ch) {
            int g = ch * 256 + tid;
            int row = g >> 3, sl = g & 7;
            int scol = ((sl ^ (row & 7)) << 2);
            const float* src = base + (size_t)row * K + scol;
            void* dst = (char*)&As[buf][0][0] + ch * 4096 + wid * 1024;
            gload_lds16(src, dst);
        }
    };

    auto compute = [&](int buf, int kt) {
        // B fragments straight from global (L2-hot 512KB/XCD)
        bf16x8 bh[2], bl[2];
#pragma unroll
        for (int nf = 0; nf < 2; ++nf) {
            int brow = wn * 32 + nf * 16 + lrow;
            size_t bo = (size_t)brow * K + k0 + kt * 32 + lkh * 8;
            bh[nf] = *(const bf16x8*)(Bh + bo);
            bl[nf] = *(const bf16x8*)(Bl + bo);
        }
        // A fragments: swizzled ds_read (2x b128 per mf) + consumer convert
        bf16x8 ah[4], al[4];
#pragma unroll
        for (int mf = 0; mf < 4; ++mf) {
            int row = wm * 64 + mf * 16 + lrow;
            int r7 = row & 7;
            int s0 = (2 * lkh) ^ r7;
            int s1 = (2 * lkh + 1) ^ r7;
            float4 x0 = *(const float4*)&As[buf][row][s0 << 2];
            float4 x1 = *(const float4*)&As[buf][row][s1 << 2];
            PK4 ph, pl;
            ph.u[0] = cvt_pk_bf16(x0.x, x0.y);
            ph.u[1] = cvt_pk_bf16(x0.z, x0.w);
            ph.u[2] = cvt_pk_bf16(x1.x, x1.y);
            ph.u[3] = cvt_pk_bf16(x1.z, x1.w);
            float r0 = x0.x - __uint_as_float(ph.u[0] << 16);
            float r1 = x0.y - __uint_as_float(ph.u[0] & 0xFFFF0000u);
            float r2 = x0.z - __uint_as_float(ph.u[1] << 16);
            float r3 = x0.w - __uint_as_float(ph.u[1] & 0xFFFF0000u);
            float r4 = x1.x - __uint_as_float(ph.u[2] << 16);
            float r5 = x1.y - __uint_as_float(ph.u[2] & 0xFFFF0000u);
            float r6 = x1.z - __uint_as_float(ph.u[3] << 16);
            float r7f = x1.w - __uint_as_float(ph.u[3] & 0xFFFF0000u);
            pl.u[0] = cvt_pk_bf16(r0, r1);
            pl.u[1] = cvt_pk_bf16(r2, r3);
            pl.u[2] = cvt_pk_bf16(r4, r5);
            pl.u[3] = cvt_pk_bf16(r6, r7f);
            ah[mf] = ph.v;
            al[mf] = pl.v;
        }
#pragma unroll
        for (int mf = 0; mf < 4; ++mf)
#pragma unroll
            for (int nf = 0; nf < 2; ++nf) {
                acc[mf][nf] = __builtin_amdgcn_mfma_f32_16x16x32_bf16(ah[mf], bh[nf], acc[mf][nf], 0, 0, 0);
                acc[mf][nf] = __builtin_amdgcn_mfma_f32_16x16x32_bf16(al[mf], bh[nf], acc[mf][nf], 0, 0, 0);
                acc[mf][nf] = __builtin_amdgcn_mfma_f32_16x16x32_bf16(ah[mf], bl[nf], acc[mf][nf], 0, 0, 0);
            }
    };

    // m97 2-phase: STAGE(next) issued before compute(cur); one barrier/step.
    stage(0, 0);
    __syncthreads();
    int buf = 0;
    for (int kt = 0; kt < iters; ++kt) {
        if (kt + 1 < iters) stage(buf ^ 1, kt + 1);
        compute(buf, kt);
        __syncthreads();
        buf ^= 1;
    }

    // C/D layout: col = lane&15, row = (lane>>4)*4 + reg. NT stores.
    float* out = P + (size_t)by * n * 64;
#pragma unroll
    for (int mf = 0; mf < 4; ++mf)
#pragma unroll
        for (int nf = 0; nf < 2; ++nf)
#pragma unroll
            for (int j = 0; j < 4; ++j) {
                int row = bm + wm * 64 + mf * 16 + lkh * 4 + j;
                int col = wn * 32 + nf * 16 + lrow;
                stnt(out + (size_t)row * 64 + col, acc[mf][nf][j]);
            }
}

__global__ void reduce8_k(float4* __restrict__ p, size_t q) {
    size_t i = (size_t)blockIdx.x * blockDim.x + threadIdx.x;
    if (i >= q) return;
    float4 a = p[i];
#pragma unroll
    for (int z = 1; z < 8; ++z) {
        float4 b = ldnt4((const float*)(p + i + (size_t)z * q));
        a.x += b.x; a.y += b.y; a.z += b.z; a.w += b.w;
    }
    p[i] = a;
}

// --- propagate, float4 per thread: out[i,:] = sum_e w_e*h[src_e,:] + dis^2*h[i,:] + b
template <int F, bool RELU>
__global__ void prop_k(const float* __restrict__ h, const int* __restrict__ offs,
                       const int* __restrict__ src, const float* __restrict__ w,
                       const float* __restrict__ dis, const float* __restrict__ b,
                       float* __restrict__ out, int n) {
    constexpr int LPN = F / 4;
    int t = blockIdx.x * blockDim.x + threadIdx.x;
    int node = t / LPN, q = t % LPN;
    if (node >= n) return;
    float4 acc = make_float4(0.f, 0.f, 0.f, 0.f);
    int p0 = offs[node], p1 = offs[node + 1];
    for (int p = p0; p < p1; ++p) {
        float ww = w[p];
        float4 hv = *(const float4*)(h + (size_t)src[p] * F + q * 4);
        acc.x = fmaf(ww, hv.x, acc.x);
        acc.y = fmaf(ww, hv.y, acc.y);
        acc.z = fmaf(ww, hv.z, acc.z);
        acc.w = fmaf(ww, hv.w, acc.w);
    }
    float d = dis[node];
    float ds = d * d;
    float4 hv = *(const float4*)(h + (size_t)node * F + q * 4);
    float4 bv = *(const float4*)(b + q * 4);
    acc.x = fmaf(ds, hv.x, acc.x) + bv.x;
    acc.y = fmaf(ds, hv.y, acc.y) + bv.y;
    acc.z = fmaf(ds, hv.z, acc.z) + bv.z;
    acc.w = fmaf(ds, hv.w, acc.w) + bv.w;
    if (RELU) {
        acc.x = fmaxf(acc.x, 0.f);
        acc.y = fmaxf(acc.y, 0.f);
        acc.z = fmaxf(acc.z, 0.f);
        acc.w = fmaxf(acc.w, 0.f);
    }
    *(float4*)(out + (size_t)node * F + q * 4) = acc;
}

template <int K, int FO>
__global__ void gemm_small_k(const float* __restrict__ h, const float* __restrict__ W,
                             float* __restrict__ out, int n) {
    __shared__ float Ws[K * FO];
    for (int i = threadIdx.x; i < K * FO; i += blockDim.x) Ws[i] = W[i];
    __syncthreads();
    int t = blockIdx.x * blockDim.x + threadIdx.x;
    int node = t / FO, c = t % FO;
    if (node >= n) return;
    const float4* h4 = (const float4*)(h + (size_t)node * K);
    float acc = 0.f;
#pragma unroll
    for (int k4 = 0; k4 < K / 4; ++k4) {
        float4 v = h4[k4];
        acc = fmaf(v.x, Ws[(k4 * 4 + 0) * FO + c], acc);
        acc = fmaf(v.y, Ws[(k4 * 4 + 1) * FO + c], acc);
        acc = fmaf(v.z, Ws[(k4 * 4 + 2) * FO + c], acc);
        acc = fmaf(v.w, Ws[(k4 * 4 + 3) * FO + c], acc);
    }
    out[t] = acc;
}

// --- final propagate (F=16) + bias + softmax, float4/thread, 4 lanes/node
__global__ void prop_softmax_k(const float* __restrict__ h, const int* __restrict__ offs,
                               const int* __restrict__ src, const float* __restrict__ w,
                               const float* __restrict__ dis, const float* __restrict__ b,
                               float* __restrict__ out, int n) {
    int t = blockIdx.x * blockDim.x + threadIdx.x;
    int node = t >> 2, q = t & 3;
    if (node >= n) return;
    float4 acc = make_float4(0.f, 0.f, 0.f, 0.f);
    int p0 = offs[node], p1 = offs[node + 1];
    for (int p = p0; p < p1; ++p) {
        float ww = w[p];
        float4 hv = *(const float4*)(h + (size_t)src[p] * 16 + q * 4);
        acc.x = fmaf(ww, hv.x, acc.x);
        acc.y = fmaf(ww, hv.y, acc.y);
        acc.z = fmaf(ww, hv.z, acc.z);
        acc.w = fmaf(ww, hv.w, acc.w);
    }
    float d = dis[node];
    float ds = d * d;
    float4 hv = *(const float4*)(h + (size_t)node * 16 + q * 4);
    float4 bv = *(const float4*)(b + q * 4);
    acc.x = fmaf(ds, hv.x, acc.x) + bv.x;
    acc.y = fmaf(ds, hv.y, acc.y) + bv.y;
    acc.z = fmaf(ds, hv.z, acc.z) + bv.z;
    acc.w = fmaf(ds, hv.w, acc.w) + bv.w;
    float m = fmaxf(fmaxf(acc.x, acc.y), fmaxf(acc.z, acc.w));
    m = fmaxf(m, __shfl_xor(m, 1));
    m = fmaxf(m, __shfl_xor(m, 2));
    float4 e;
    e.x = __expf(acc.x - m);
    e.y = __expf(acc.y - m);
    e.z = __expf(acc.z - m);
    e.w = __expf(acc.w - m);
    float s = e.x + e.y + e.z + e.w;
    s += __shfl_xor(s, 1);
    s += __shfl_xor(s, 2);
    float inv = 1.f / s;
    e.x *= inv; e.y *= inv; e.z *= inv; e.w *= inv;
    *(float4*)(out + (size_t)node * 16 + q * 4) = e;
}

extern "C" void kernel_launch(void* const* d_in, const int* in_sizes, int n_in,
                              void* d_out, int out_size, void* d_ws, size_t ws_size,
                              hipStream_t stream) {
    const float* x  = (const float*)d_in[0];
    const int*   ei = (const int*)d_in[1];
    const float* W1 = (const float*)d_in[2];
    const float* b1 = (const float*)d_in[3];
    const float* W2 = (const float*)d_in[4];
    const float* b2 = (const float*)d_in[5];
    const float* W3 = (const float*)d_in[6];
    const float* b3 = (const float*)d_in[7];
    float* out = (float*)d_out;

    const int n = in_sizes[2] / 64;
    const int K = in_sizes[0] / n;
    const int E = in_sizes[1] / 2;

    char* ws = (char*)d_ws;
    size_t off = 0;
    auto alloc = [&](size_t bytes) {
        char* p = ws + off;
        off = (off + bytes + 255) & ~(size_t)255;
        return p;
    };
    int*   flag   = (int*)  alloc(4);
    int*   cnt    = (int*)  alloc((size_t)n * 4);
    int*   cursor = (int*)  alloc((size_t)n * 4);
    int*   offs   = (int*)  alloc((size_t)(n + 1) * 4);
    float* dis    = (float*)alloc((size_t)n * 4);
    int*   csrs   = (int*)  alloc((size_t)E * 4);
    float* csrw   = (float*)alloc((size_t)E * 4);
    unsigned short* Btw = (unsigned short*)alloc((size_t)2 * 64 * K * 2);
    float* P      = (float*)alloc((size_t)8 * n * 64 * 4);  // partials; plane 0 = H0
    float* H1     = (float*)alloc((size_t)n * 64 * 4);
    float* H2a    = (float*)alloc((size_t)n * 32 * 4);
    float* H2     = (float*)alloc((size_t)n * 32 * 4);
    float* H3a    = (float*)alloc((size_t)n * 16 * 4);
    (void)ws_size; (void)n_in; (void)out_size;

    init_k<<<(n + 255) / 256, 256, 0, stream>>>(ei, flag, cnt, n);
    count_deg_k<<<(E + 255) / 256, 256, 0, stream>>>(ei, E, flag, cnt);
    scan_k<<<1, 1024, 0, stream>>>(cnt, offs, dis, cursor, n);
    fill_csr_k<<<(E + 255) / 256, 256, 0, stream>>>(ei, E, flag, offs, cursor, dis, csrs, csrw);
    prep_w1_k<<<(K * 64 + 255) / 256, 256, 0, stream>>>(W1, Btw, K);

    gemm1_mfma_k<<<(n / 128) * 8, 256, 0, stream>>>(x, Btw, P, n, K, K / 8);
    size_t q = (size_t)n * 64 / 4;
    reduce8_k<<<(int)((q + 255) / 256), 256, 0, stream>>>((float4*)P, q);

    prop_k<64, true><<<(n * 16 + 255) / 256, 256, 0, stream>>>(P, offs, csrs, csrw, dis, b1, H1, n);
    gemm_small_k<64, 32><<<(n * 32 + 255) / 256, 256, 0, stream>>>(H1, W2, H2a, n);
    prop_k<32, true><<<(n * 8 + 255) / 256, 256, 0, stream>>>(H2a, offs, csrs, csrw, dis, b2, H2, n);
    gemm_small_k<32, 16><<<(n * 16 + 255) / 256, 256, 0, stream>>>(H2, W3, H3a, n);
    prop_softmax_k<<<(n * 4 + 255) / 256, 256, 0, stream>>>(H3a, offs, csrs, csrw, dis, b3, out, n);
}

// Round 9
// 436.924 us; speedup vs baseline: 2.6553x; 1.0963x over previous
//
#include <hip/hip_runtime.h>

// ---------------------------------------------------------------------------
// 3-layer GCN (PyG gcn_norm semantics) on MI355X.
//   0. init: zero cnt + flag probe + prep W1 (fused)
//   1. degree count ; scan -> CSR offsets (+dis, +cursor=0) ; fill CSR
//   2. H0 = x @ W1 split-bf16 MFMA (xh*Wh + xl*Wh + xh*Wl), K-split x8
//      (grid 1024 = 4 blocks/CU -- R7 counters showed 23% occupancy was the
//      binding constraint; loop body is R5's verified-best, untouched).
//   3. reduce8 -> H0 ; fused prop64+gemm2 (H0->H2a) ; fused prop32+gemm3
//      (H2a->H3a) ; prop_softmax (H3a->out)
// ---------------------------------------------------------------------------

typedef __attribute__((ext_vector_type(8))) short bf16x8;
typedef __attribute__((ext_vector_type(4))) float f32x4;
typedef __attribute__((ext_vector_type(4))) float fv4;

__device__ __forceinline__ float4 ldnt4(const float* p) {
    fv4 v = __builtin_nontemporal_load((const fv4*)p);
    return make_float4(v.x, v.y, v.z, v.w);
}
__device__ __forceinline__ void stnt(float* p, float v) {
    __builtin_nontemporal_store(v, p);
}

__device__ __forceinline__ unsigned cvt_pk_bf16(float a, float b) {
    // D[15:0] = bf16_rne(a), D[31:16] = bf16_rne(b)
    unsigned r;
    asm("v_cvt_pk_bf16_f32 %0, %1, %2" : "=v"(r) : "v"(a), "v"(b));
    return r;
}

__device__ __forceinline__ unsigned short f2bf_rne(float f) {
    unsigned u = __float_as_uint(f);
    unsigned r = (u + 0x7FFFu + ((u >> 16) & 1u)) >> 16;
    return (unsigned short)r;
}

// --- fused: zero cnt + int64-vs-int32 probe + W1 split/transpose
__global__ void init_prep_k(const int* __restrict__ ei, int* __restrict__ flag,
                            int* __restrict__ cnt, int n,
                            const float* __restrict__ W1,
                            unsigned short* __restrict__ Bt, int K) {
    int t = blockIdx.x * blockDim.x + threadIdx.x;
    if (t < n) cnt[t] = 0;
    if (t == 0) {
        int f = 1;
        for (int i = 0; i < 256; ++i) {
            if (ei[2 * i + 1] != 0) { f = 0; break; }
        }
        *flag = f;
    }
    if (t < K * 64) {
        int nn = t & 63, k = t >> 6;
        float f = W1[(size_t)k * 64 + nn];
        unsigned short hi = f2bf_rne(f);
        float hf = __uint_as_float((unsigned)hi << 16);
        unsigned short lo = f2bf_rne(f - hf);
        Bt[(size_t)nn * K + k] = hi;
        Bt[(size_t)64 * K + (size_t)nn * K + k] = lo;
    }
}

__device__ __forceinline__ int edge_val(const int* __restrict__ ei, long long idx, int f64) {
    return f64 ? ei[2 * idx] : ei[(int)idx];
}

__global__ void count_deg_k(const int* __restrict__ ei, int E, const int* __restrict__ flag,
                            int* __restrict__ cnt) {
    int e = blockIdx.x * blockDim.x + threadIdx.x;
    if (e >= E) return;
    int f = *flag;
    int c = edge_val(ei, (long long)E + e, f);
    atomicAdd(&cnt[c], 1);
}

// scan + dis + cursor init, single block
__global__ void scan_k(const int* __restrict__ cnt, int* __restrict__ offs,
                       float* __restrict__ dis, int* __restrict__ cursor, int n) {
    __shared__ int sums[1024];
    const int t = threadIdx.x;
    const int base = t * 16;
    int loc[16];
    int s = 0;
#pragma unroll
    for (int i = 0; i < 16; ++i) {
        loc[i] = s;
        int idx = base + i;
        s += (idx < n) ? cnt[idx] : 0;
    }
    sums[t] = s;
    __syncthreads();
    for (int o = 1; o < 1024; o <<= 1) {
        int v = (t >= o) ? sums[t - o] : 0;
        __syncthreads();
        sums[t] += v;
        __syncthreads();
    }
    int tbase = (t == 0) ? 0 : sums[t - 1];
#pragma unroll
    for (int i = 0; i < 16; ++i) {
        int idx = base + i;
        if (idx < n) {
            offs[idx] = tbase + loc[i];
            cursor[idx] = 0;
            dis[idx] = rsqrtf((float)(cnt[idx] + 1));  // +1: self loop
        }
    }
    if (t == 1023) offs[n] = sums[1023];
}

__global__ void fill_csr_k(const int* __restrict__ ei, int E, const int* __restrict__ flag,
                           const int* __restrict__ offs, int* __restrict__ cursor,
                           const float* __restrict__ dis, int* __restrict__ src,
                           float* __restrict__ w) {
    int e = blockIdx.x * blockDim.x + threadIdx.x;
    if (e >= E) return;
    int f = *flag;
    int r = edge_val(ei, (long long)e, f);
    int c = edge_val(ei, (long long)E + e, f);
    int pos = offs[c] + atomicAdd(&cursor[c], 1);
    src[pos] = r;
    w[pos] = dis[r] * dis[c];
}

// --- GEMM1: [n x K] fp32 @ Bt[2][64][K] -> P[kz][n][64], split-bf16 MFMA.
// BM=128, BN=64, BK=32, 256 thr = 4 waves (2m x 2n), wave tile 64x32.
// K-split x8 (grid 1024 = 4 blocks/CU). Loop body identical to R5-best.
__global__ __launch_bounds__(256) void gemm1_mfma_k(
    const float* __restrict__ A, const unsigned short* __restrict__ Bt,
    float* __restrict__ P, int n, int K, int kchunk) {
    __shared__ unsigned short As[2][128][40];  // [hi/lo][row][k], pad 40
    const int tid = threadIdx.x;
    const int lane = tid & 63;
    const int wid = tid >> 6;
    const int wm = wid >> 1, wn = wid & 1;
    const int lrow = lane & 15, lkh = lane >> 4;
    // XCD grouping: round-robin dispatch -> XCD i sees only by==i (512KB B)
    const int bid = blockIdx.x;
    const int by = bid & 7;
    const int bx = bid >> 3;
    const int bm = bx * 128;
    const int k0 = by * kchunk;
    const int iters = kchunk / 32;  // K=16384 /8 /32 = 64

    const unsigned short* Bh = Bt;
    const unsigned short* Bl = Bt + (size_t)64 * K;

    f32x4 acc[4][2] = {};
    float4 st[4];

    auto loadA = [&](int kt) {
#pragma unroll
        for (int i = 0; i < 4; ++i) {
            int v = tid + i * 256;
            int r = v >> 3, c = (v & 7) * 4;
            st[i] = ldnt4(A + (size_t)(bm + r) * K + k0 + kt * 32 + c);
        }
    };

    loadA(0);
    for (int kt = 0; kt < iters; ++kt) {
        // B fragments from global (L2-resident; NOT nt)
        bf16x8 bh[2], bl[2];
#pragma unroll
        for (int nf = 0; nf < 2; ++nf) {
            int brow = wn * 32 + nf * 16 + lrow;
            size_t bo = (size_t)brow * K + k0 + kt * 32 + lkh * 8;
            bh[nf] = *(const bf16x8*)(Bh + bo);
            bl[nf] = *(const bf16x8*)(Bl + bo);
        }
        // convert staged A regs -> hi/lo bf16 -> LDS (cvt_pk)
#pragma unroll
        for (int i = 0; i < 4; ++i) {
            int v = tid + i * 256;
            int r = v >> 3, c = (v & 7) * 4;
            float f0 = st[i].x, f1 = st[i].y, f2 = st[i].z, f3 = st[i].w;
            unsigned h01 = cvt_pk_bf16(f0, f1);
            unsigned h23 = cvt_pk_bf16(f2, f3);
            float r0 = f0 - __uint_as_float(h01 << 16);
            float r1 = f1 - __uint_as_float(h01 & 0xFFFF0000u);
            float r2 = f2 - __uint_as_float(h23 << 16);
            float r3 = f3 - __uint_as_float(h23 & 0xFFFF0000u);
            unsigned l01 = cvt_pk_bf16(r0, r1);
            unsigned l23 = cvt_pk_bf16(r2, r3);
            *(uint2*)&As[0][r][c] = make_uint2(h01, h23);
            *(uint2*)&As[1][r][c] = make_uint2(l01, l23);
        }
        __syncthreads();
        if (kt + 1 < iters) loadA(kt + 1);  // prefetch under MFMA
        bf16x8 ah[4], al[4];
#pragma unroll
        for (int mf = 0; mf < 4; ++mf) {
            int row = wm * 64 + mf * 16 + lrow;
            ah[mf] = *(const bf16x8*)&As[0][row][lkh * 8];
            al[mf] = *(const bf16x8*)&As[1][row][lkh * 8];
        }
#pragma unroll
        for (int mf = 0; mf < 4; ++mf)
#pragma unroll
            for (int nf = 0; nf < 2; ++nf) {
                acc[mf][nf] = __builtin_amdgcn_mfma_f32_16x16x32_bf16(ah[mf], bh[nf], acc[mf][nf], 0, 0, 0);
                acc[mf][nf] = __builtin_amdgcn_mfma_f32_16x16x32_bf16(al[mf], bh[nf], acc[mf][nf], 0, 0, 0);
                acc[mf][nf] = __builtin_amdgcn_mfma_f32_16x16x32_bf16(ah[mf], bl[nf], acc[mf][nf], 0, 0, 0);
            }
        __syncthreads();
    }
    // C/D layout: col = lane&15, row = (lane>>4)*4 + reg. NT stores.
    float* out = P + (size_t)by * n * 64;
#pragma unroll
    for (int mf = 0; mf < 4; ++mf)
#pragma unroll
        for (int nf = 0; nf < 2; ++nf)
#pragma unroll
            for (int j = 0; j < 4; ++j) {
                int row = bm + wm * 64 + mf * 16 + lkh * 4 + j;
                int col = wn * 32 + nf * 16 + lrow;
                stnt(out + (size_t)row * 64 + col, acc[mf][nf][j]);
            }
}

__global__ void reduce8_k(float4* __restrict__ p, size_t q) {
    size_t i = (size_t)blockIdx.x * blockDim.x + threadIdx.x;
    if (i >= q) return;
    float4 a = p[i];
#pragma unroll
    for (int z = 1; z < 8; ++z) {
        float4 b = ldnt4((const float*)(p + i + (size_t)z * q));
        a.x += b.x; a.y += b.y; a.z += b.z; a.w += b.w;
    }
    p[i] = a;
}

// --- fused: H1 = relu(Agg(H0)+b1) ; H2a = H1 @ W2.  16 thr/node, 16 nodes/blk.
__global__ __launch_bounds__(256) void prop64_gemm2_k(
    const float* __restrict__ h, const int* __restrict__ offs,
    const int* __restrict__ src, const float* __restrict__ w,
    const float* __restrict__ dis, const float* __restrict__ b1,
    const float* __restrict__ W2, float* __restrict__ H2a, int n) {
    __shared__ float Ws[64 * 32];
    __shared__ float rows[16][68];  // pad 68: nl-conflict-free broadcast reads
    const int tid = threadIdx.x;
    for (int i = tid; i < 64 * 32; i += 256) Ws[i] = W2[i];
    const int t = blockIdx.x * 256 + tid;
    const int node = t >> 4, q = t & 15, nl = tid >> 4;
    float4 acc = make_float4(0.f, 0.f, 0.f, 0.f);
    int p0 = offs[node], p1 = offs[node + 1];
    for (int p = p0; p < p1; ++p) {
        float ww = w[p];
        float4 hv = *(const float4*)(h + (size_t)src[p] * 64 + q * 4);
        acc.x = fmaf(ww, hv.x, acc.x);
        acc.y = fmaf(ww, hv.y, acc.y);
        acc.z = fmaf(ww, hv.z, acc.z);
        acc.w = fmaf(ww, hv.w, acc.w);
    }
    float d = dis[node];
    float ds = d * d;
    float4 hv = *(const float4*)(h + (size_t)node * 64 + q * 4);
    float4 bv = *(const float4*)(b1 + q * 4);
    acc.x = fmaxf(fmaf(ds, hv.x, acc.x) + bv.x, 0.f);
    acc.y = fmaxf(fmaf(ds, hv.y, acc.y) + bv.y, 0.f);
    acc.z = fmaxf(fmaf(ds, hv.z, acc.z) + bv.z, 0.f);
    acc.w = fmaxf(fmaf(ds, hv.w, acc.w) + bv.w, 0.f);
    *(float4*)&rows[nl][q * 4] = acc;
    __syncthreads();
    // gemm2: each thread -> 2 output cols
    const int c0 = q * 2;
    float s0 = 0.f, s1 = 0.f;
#pragma unroll
    for (int k = 0; k < 64; ++k) {
        float v = rows[nl][k];
        s0 = fmaf(v, Ws[k * 32 + c0], s0);
        s1 = fmaf(v, Ws[k * 32 + c0 + 1], s1);
    }
    H2a[(size_t)node * 32 + c0] = s0;
    H2a[(size_t)node * 32 + c0 + 1] = s1;
}

// --- fused: H2 = relu(Agg(H2a)+b2) ; H3a = H2 @ W3.  8 thr/node, 32 nodes/blk.
__global__ __launch_bounds__(256) void prop32_gemm3_k(
    const float* __restrict__ h, const int* __restrict__ offs,
    const int* __restrict__ src, const float* __restrict__ w,
    const float* __restrict__ dis, const float* __restrict__ b2,
    const float* __restrict__ W3, float* __restrict__ H3a, int n) {
    __shared__ float Ws[32 * 16];
    __shared__ float rows[32][36];  // pad 36
    const int tid = threadIdx.x;
    for (int i = tid; i < 32 * 16; i += 256) Ws[i] = W3[i];
    const int t = blockIdx.x * 256 + tid;
    const int node = t >> 3, q = t & 7, nl = tid >> 3;
    float4 acc = make_float4(0.f, 0.f, 0.f, 0.f);
    int p0 = offs[node], p1 = offs[node + 1];
    for (int p = p0; p < p1; ++p) {
        float ww = w[p];
        float4 hv = *(const float4*)(h + (size_t)src[p] * 32 + q * 4);
        acc.x = fmaf(ww, hv.x, acc.x);
        acc.y = fmaf(ww, hv.y, acc.y);
        acc.z = fmaf(ww, hv.z, acc.z);
        acc.w = fmaf(ww, hv.w, acc.w);
    }
    float d = dis[node];
    float ds = d * d;
    float4 hv = *(const float4*)(h + (size_t)node * 32 + q * 4);
    float4 bv = *(const float4*)(b2 + q * 4);
    acc.x = fmaxf(fmaf(ds, hv.x, acc.x) + bv.x, 0.f);
    acc.y = fmaxf(fmaf(ds, hv.y, acc.y) + bv.y, 0.f);
    acc.z = fmaxf(fmaf(ds, hv.z, acc.z) + bv.z, 0.f);
    acc.w = fmaxf(fmaf(ds, hv.w, acc.w) + bv.w, 0.f);
    *(float4*)&rows[nl][q * 4] = acc;
    __syncthreads();
    const int c0 = q * 2;
    float s0 = 0.f, s1 = 0.f;
#pragma unroll
    for (int k = 0; k < 32; ++k) {
        float v = rows[nl][k];
        s0 = fmaf(v, Ws[k * 16 + c0], s0);
        s1 = fmaf(v, Ws[k * 16 + c0 + 1], s1);
    }
    H3a[(size_t)node * 16 + c0] = s0;
    H3a[(size_t)node * 16 + c0 + 1] = s1;
}

// --- final propagate (F=16) + bias + softmax, float4/thread, 4 lanes/node
__global__ void prop_softmax_k(const float* __restrict__ h, const int* __restrict__ offs,
                               const int* __restrict__ src, const float* __restrict__ w,
                               const float* __restrict__ dis, const float* __restrict__ b,
                               float* __restrict__ out, int n) {
    int t = blockIdx.x * blockDim.x + threadIdx.x;
    int node = t >> 2, q = t & 3;
    if (node >= n) return;
    float4 acc = make_float4(0.f, 0.f, 0.f, 0.f);
    int p0 = offs[node], p1 = offs[node + 1];
    for (int p = p0; p < p1; ++p) {
        float ww = w[p];
        float4 hv = *(const float4*)(h + (size_t)src[p] * 16 + q * 4);
        acc.x = fmaf(ww, hv.x, acc.x);
        acc.y = fmaf(ww, hv.y, acc.y);
        acc.z = fmaf(ww, hv.z, acc.z);
        acc.w = fmaf(ww, hv.w, acc.w);
    }
    float d = dis[node];
    float ds = d * d;
    float4 hv = *(const float4*)(h + (size_t)node * 16 + q * 4);
    float4 bv = *(const float4*)(b + q * 4);
    acc.x = fmaf(ds, hv.x, acc.x) + bv.x;
    acc.y = fmaf(ds, hv.y, acc.y) + bv.y;
    acc.z = fmaf(ds, hv.z, acc.z) + bv.z;
    acc.w = fmaf(ds, hv.w, acc.w) + bv.w;
    float m = fmaxf(fmaxf(acc.x, acc.y), fmaxf(acc.z, acc.w));
    m = fmaxf(m, __shfl_xor(m, 1));
    m = fmaxf(m, __shfl_xor(m, 2));
    float4 e;
    e.x = __expf(acc.x - m);
    e.y = __expf(acc.y - m);
    e.z = __expf(acc.z - m);
    e.w = __expf(acc.w - m);
    float s = e.x + e.y + e.z + e.w;
    s += __shfl_xor(s, 1);
    s += __shfl_xor(s, 2);
    float inv = 1.f / s;
    e.x *= inv; e.y *= inv; e.z *= inv; e.w *= inv;
    *(float4*)(out + (size_t)node * 16 + q * 4) = e;
}

extern "C" void kernel_launch(void* const* d_in, const int* in_sizes, int n_in,
                              void* d_out, int out_size, void* d_ws, size_t ws_size,
                              hipStream_t stream) {
    const float* x  = (const float*)d_in[0];
    const int*   ei = (const int*)d_in[1];
    const float* W1 = (const float*)d_in[2];
    const float* b1 = (const float*)d_in[3];
    const float* W2 = (const float*)d_in[4];
    const float* b2 = (const float*)d_in[5];
    const float* W3 = (const float*)d_in[6];
    const float* b3 = (const float*)d_in[7];
    float* out = (float*)d_out;

    const int n = in_sizes[2] / 64;
    const int K = in_sizes[0] / n;
    const int E = in_sizes[1] / 2;

    char* ws = (char*)d_ws;
    size_t off = 0;
    auto alloc = [&](size_t bytes) {
        char* p = ws + off;
        off = (off + bytes + 255) & ~(size_t)255;
        return p;
    };
    int*   flag   = (int*)  alloc(4);
    int*   cnt    = (int*)  alloc((size_t)n * 4);
    int*   cursor = (int*)  alloc((size_t)n * 4);
    int*   offs   = (int*)  alloc((size_t)(n + 1) * 4);
    float* dis    = (float*)alloc((size_t)n * 4);
    int*   csrs   = (int*)  alloc((size_t)E * 4);
    float* csrw   = (float*)alloc((size_t)E * 4);
    unsigned short* Btw = (unsigned short*)alloc((size_t)2 * 64 * K * 2);
    float* P      = (float*)alloc((size_t)8 * n * 64 * 4);  // partials; plane 0 = H0
    float* H2a    = (float*)alloc((size_t)n * 32 * 4);
    float* H3a    = (float*)alloc((size_t)n * 16 * 4);
    (void)ws_size; (void)n_in; (void)out_size;

    init_prep_k<<<(K * 64 + 255) / 256, 256, 0, stream>>>(ei, flag, cnt, n, W1, Btw, K);
    count_deg_k<<<(E + 255) / 256, 256, 0, stream>>>(ei, E, flag, cnt);
    scan_k<<<1, 1024, 0, stream>>>(cnt, offs, dis, cursor, n);
    fill_csr_k<<<(E + 255) / 256, 256, 0, stream>>>(ei, E, flag, offs, cursor, dis, csrs, csrw);

    gemm1_mfma_k<<<(n / 128) * 8, 256, 0, stream>>>(x, Btw, P, n, K, K / 8);
    size_t q = (size_t)n * 64 / 4;
    reduce8_k<<<(int)((q + 255) / 256), 256, 0, stream>>>((float4*)P, q);

    prop64_gemm2_k<<<n * 16 / 256, 256, 0, stream>>>(P, offs, csrs, csrw, dis, b1, W2, H2a, n);
    prop32_gemm3_k<<<n * 8 / 256, 256, 0, stream>>>(H2a, offs, csrs, csrw, dis, b2, W3, H3a, n);
    prop_softmax_k<<<n * 4 / 256, 256, 0, stream>>>(H3a, offs, csrs, csrw, dis, b3, out, n);
}

// Round 10
// 404.476 us; speedup vs baseline: 2.8684x; 1.0802x over previous
//
#include <hip/hip_runtime.h>

// ---------------------------------------------------------------------------
// 3-layer GCN (PyG gcn_norm semantics) on MI355X.
// R10 = measured-best recombination:
//   gemm1: R5 exact (K-split 4, paired-XCD swizzle, NT A-loads, cvt_pk)
//   tail:  R9 fused (init+prep, prop64+gemm2, prop32+gemm3), reduce4
// ---------------------------------------------------------------------------

typedef __attribute__((ext_vector_type(8))) short bf16x8;
typedef __attribute__((ext_vector_type(4))) float f32x4;
typedef __attribute__((ext_vector_type(4))) float fv4;

__device__ __forceinline__ float4 ldnt4(const float* p) {
    fv4 v = __builtin_nontemporal_load((const fv4*)p);
    return make_float4(v.x, v.y, v.z, v.w);
}
__device__ __forceinline__ void stnt(float* p, float v) {
    __builtin_nontemporal_store(v, p);
}

__device__ __forceinline__ unsigned cvt_pk_bf16(float a, float b) {
    // D[15:0] = bf16_rne(a), D[31:16] = bf16_rne(b)
    unsigned r;
    asm("v_cvt_pk_bf16_f32 %0, %1, %2" : "=v"(r) : "v"(a), "v"(b));
    return r;
}

__device__ __forceinline__ unsigned short f2bf_rne(float f) {
    unsigned u = __float_as_uint(f);
    unsigned r = (u + 0x7FFFu + ((u >> 16) & 1u)) >> 16;
    return (unsigned short)r;
}

// --- fused: zero cnt + int64-vs-int32 probe + W1 split/transpose
__global__ void init_prep_k(const int* __restrict__ ei, int* __restrict__ flag,
                            int* __restrict__ cnt, int n,
                            const float* __restrict__ W1,
                            unsigned short* __restrict__ Bt, int K) {
    int t = blockIdx.x * blockDim.x + threadIdx.x;
    if (t < n) cnt[t] = 0;
    if (t == 0) {
        int f = 1;
        for (int i = 0; i < 256; ++i) {
            if (ei[2 * i + 1] != 0) { f = 0; break; }
        }
        *flag = f;
    }
    if (t < K * 64) {
        int nn = t & 63, k = t >> 6;
        float f = W1[(size_t)k * 64 + nn];
        unsigned short hi = f2bf_rne(f);
        float hf = __uint_as_float((unsigned)hi << 16);
        unsigned short lo = f2bf_rne(f - hf);
        Bt[(size_t)nn * K + k] = hi;
        Bt[(size_t)64 * K + (size_t)nn * K + k] = lo;
    }
}

__device__ __forceinline__ int edge_val(const int* __restrict__ ei, long long idx, int f64) {
    return f64 ? ei[2 * idx] : ei[(int)idx];
}

__global__ void count_deg_k(const int* __restrict__ ei, int E, const int* __restrict__ flag,
                            int* __restrict__ cnt) {
    int e = blockIdx.x * blockDim.x + threadIdx.x;
    if (e >= E) return;
    int f = *flag;
    int c = edge_val(ei, (long long)E + e, f);
    atomicAdd(&cnt[c], 1);
}

// scan + dis + cursor init, single block
__global__ void scan_k(const int* __restrict__ cnt, int* __restrict__ offs,
                       float* __restrict__ dis, int* __restrict__ cursor, int n) {
    __shared__ int sums[1024];
    const int t = threadIdx.x;
    const int base = t * 16;
    int loc[16];
    int s = 0;
#pragma unroll
    for (int i = 0; i < 16; ++i) {
        loc[i] = s;
        int idx = base + i;
        s += (idx < n) ? cnt[idx] : 0;
    }
    sums[t] = s;
    __syncthreads();
    for (int o = 1; o < 1024; o <<= 1) {
        int v = (t >= o) ? sums[t - o] : 0;
        __syncthreads();
        sums[t] += v;
        __syncthreads();
    }
    int tbase = (t == 0) ? 0 : sums[t - 1];
#pragma unroll
    for (int i = 0; i < 16; ++i) {
        int idx = base + i;
        if (idx < n) {
            offs[idx] = tbase + loc[i];
            cursor[idx] = 0;
            dis[idx] = rsqrtf((float)(cnt[idx] + 1));  // +1: self loop
        }
    }
    if (t == 1023) offs[n] = sums[1023];
}

__global__ void fill_csr_k(const int* __restrict__ ei, int E, const int* __restrict__ flag,
                           const int* __restrict__ offs, int* __restrict__ cursor,
                           const float* __restrict__ dis, int* __restrict__ src,
                           float* __restrict__ w) {
    int e = blockIdx.x * blockDim.x + threadIdx.x;
    if (e >= E) return;
    int f = *flag;
    int r = edge_val(ei, (long long)e, f);
    int c = edge_val(ei, (long long)E + e, f);
    int pos = offs[c] + atomicAdd(&cursor[c], 1);
    src[pos] = r;
    w[pos] = dis[r] * dis[c];
}

// --- GEMM1 (R5 exact): [n x K] fp32 @ Bt[2][64][K] -> P[kz][n][64].
// BM=128, BN=64, BK=32, 256 thr = 4 waves (2m x 2n), wave tile 64x32.
// K-split x4. A loads NT (bypass L2), B loads cached (L2-resident per XCD).
__global__ __launch_bounds__(256) void gemm1_mfma_k(
    const float* __restrict__ A, const unsigned short* __restrict__ Bt,
    float* __restrict__ P, int n, int K, int kchunk) {
    __shared__ unsigned short As[2][128][40];  // [hi/lo][row][k], pad 40
    const int tid = threadIdx.x;
    const int lane = tid & 63;
    const int wid = tid >> 6;
    const int wm = wid >> 1, wn = wid & 1;
    const int lrow = lane & 15, lkh = lane >> 4;
    // XCD-grouped swizzle: XCD pair {2y,2y+1} owns K-chunk y -> its 2MB of B
    const int bid = blockIdx.x;
    const int by = (bid & 7) >> 1;
    const int bx = ((bid >> 3) << 1) | (bid & 1);
    const int bm = bx * 128;
    const int k0 = by * kchunk;
    const int iters = kchunk / 32;  // K=16384 /4 /32 = 128

    const unsigned short* Bh = Bt;
    const unsigned short* Bl = Bt + (size_t)64 * K;

    f32x4 acc[4][2] = {};
    float4 st[4];

    auto loadA = [&](int kt) {
#pragma unroll
        for (int i = 0; i < 4; ++i) {
            int v = tid + i * 256;
            int r = v >> 3, c = (v & 7) * 4;
            st[i] = ldnt4(A + (size_t)(bm + r) * K + k0 + kt * 32 + c);
        }
    };

    loadA(0);
    for (int kt = 0; kt < iters; ++kt) {
        // B fragments from global (L2-resident; NOT nt)
        bf16x8 bh[2], bl[2];
#pragma unroll
        for (int nf = 0; nf < 2; ++nf) {
            int brow = wn * 32 + nf * 16 + lrow;
            size_t bo = (size_t)brow * K + k0 + kt * 32 + lkh * 8;
            bh[nf] = *(const bf16x8*)(Bh + bo);
            bl[nf] = *(const bf16x8*)(Bl + bo);
        }
        // convert staged A regs -> hi/lo bf16 -> LDS (cvt_pk)
#pragma unroll
        for (int i = 0; i < 4; ++i) {
            int v = tid + i * 256;
            int r = v >> 3, c = (v & 7) * 4;
            float f0 = st[i].x, f1 = st[i].y, f2 = st[i].z, f3 = st[i].w;
            unsigned h01 = cvt_pk_bf16(f0, f1);
            unsigned h23 = cvt_pk_bf16(f2, f3);
            float r0 = f0 - __uint_as_float(h01 << 16);
            float r1 = f1 - __uint_as_float(h01 & 0xFFFF0000u);
            float r2 = f2 - __uint_as_float(h23 << 16);
            float r3 = f3 - __uint_as_float(h23 & 0xFFFF0000u);
            unsigned l01 = cvt_pk_bf16(r0, r1);
            unsigned l23 = cvt_pk_bf16(r2, r3);
            *(uint2*)&As[0][r][c] = make_uint2(h01, h23);
            *(uint2*)&As[1][r][c] = make_uint2(l01, l23);
        }
        __syncthreads();
        if (kt + 1 < iters) loadA(kt + 1);  // prefetch under MFMA
        bf16x8 ah[4], al[4];
#pragma unroll
        for (int mf = 0; mf < 4; ++mf) {
            int row = wm * 64 + mf * 16 + lrow;
            ah[mf] = *(const bf16x8*)&As[0][row][lkh * 8];
            al[mf] = *(const bf16x8*)&As[1][row][lkh * 8];
        }
#pragma unroll
        for (int mf = 0; mf < 4; ++mf)
#pragma unroll
            for (int nf = 0; nf < 2; ++nf) {
                acc[mf][nf] = __builtin_amdgcn_mfma_f32_16x16x32_bf16(ah[mf], bh[nf], acc[mf][nf], 0, 0, 0);
                acc[mf][nf] = __builtin_amdgcn_mfma_f32_16x16x32_bf16(al[mf], bh[nf], acc[mf][nf], 0, 0, 0);
                acc[mf][nf] = __builtin_amdgcn_mfma_f32_16x16x32_bf16(ah[mf], bl[nf], acc[mf][nf], 0, 0, 0);
            }
        __syncthreads();
    }
    // C/D layout: col = lane&15, row = (lane>>4)*4 + reg. NT stores.
    float* out = P + (size_t)by * n * 64;
#pragma unroll
    for (int mf = 0; mf < 4; ++mf)
#pragma unroll
        for (int nf = 0; nf < 2; ++nf)
#pragma unroll
            for (int j = 0; j < 4; ++j) {
                int row = bm + wm * 64 + mf * 16 + lkh * 4 + j;
                int col = wn * 32 + nf * 16 + lrow;
                stnt(out + (size_t)row * 64 + col, acc[mf][nf][j]);
            }
}

__global__ void reduce4_k(float4* __restrict__ p, size_t q) {
    size_t i = (size_t)blockIdx.x * blockDim.x + threadIdx.x;
    if (i >= q) return;
    float4 a = p[i];
#pragma unroll
    for (int z = 1; z < 4; ++z) {
        float4 b = ldnt4((const float*)(p + i + (size_t)z * q));
        a.x += b.x; a.y += b.y; a.z += b.z; a.w += b.w;
    }
    p[i] = a;
}

// --- fused: H1 = relu(Agg(H0)+b1) ; H2a = H1 @ W2.  16 thr/node, 16 nodes/blk.
__global__ __launch_bounds__(256) void prop64_gemm2_k(
    const float* __restrict__ h, const int* __restrict__ offs,
    const int* __restrict__ src, const float* __restrict__ w,
    const float* __restrict__ dis, const float* __restrict__ b1,
    const float* __restrict__ W2, float* __restrict__ H2a, int n) {
    __shared__ float Ws[64 * 32];
    __shared__ float rows[16][68];  // pad 68
    const int tid = threadIdx.x;
    for (int i = tid; i < 64 * 32; i += 256) Ws[i] = W2[i];
    const int t = blockIdx.x * 256 + tid;
    const int node = t >> 4, q = t & 15, nl = tid >> 4;
    float4 acc = make_float4(0.f, 0.f, 0.f, 0.f);
    int p0 = offs[node], p1 = offs[node + 1];
    for (int p = p0; p < p1; ++p) {
        float ww = w[p];
        float4 hv = *(const float4*)(h + (size_t)src[p] * 64 + q * 4);
        acc.x = fmaf(ww, hv.x, acc.x);
        acc.y = fmaf(ww, hv.y, acc.y);
        acc.z = fmaf(ww, hv.z, acc.z);
        acc.w = fmaf(ww, hv.w, acc.w);
    }
    float d = dis[node];
    float ds = d * d;
    float4 hv = *(const float4*)(h + (size_t)node * 64 + q * 4);
    float4 bv = *(const float4*)(b1 + q * 4);
    acc.x = fmaxf(fmaf(ds, hv.x, acc.x) + bv.x, 0.f);
    acc.y = fmaxf(fmaf(ds, hv.y, acc.y) + bv.y, 0.f);
    acc.z = fmaxf(fmaf(ds, hv.z, acc.z) + bv.z, 0.f);
    acc.w = fmaxf(fmaf(ds, hv.w, acc.w) + bv.w, 0.f);
    *(float4*)&rows[nl][q * 4] = acc;
    __syncthreads();
    const int c0 = q * 2;
    float s0 = 0.f, s1 = 0.f;
#pragma unroll
    for (int k = 0; k < 64; ++k) {
        float v = rows[nl][k];
        s0 = fmaf(v, Ws[k * 32 + c0], s0);
        s1 = fmaf(v, Ws[k * 32 + c0 + 1], s1);
    }
    H2a[(size_t)node * 32 + c0] = s0;
    H2a[(size_t)node * 32 + c0 + 1] = s1;
}

// --- fused: H2 = relu(Agg(H2a)+b2) ; H3a = H2 @ W3.  8 thr/node, 32 nodes/blk.
__global__ __launch_bounds__(256) void prop32_gemm3_k(
    const float* __restrict__ h, const int* __restrict__ offs,
    const int* __restrict__ src, const float* __restrict__ w,
    const float* __restrict__ dis, const float* __restrict__ b2,
    const float* __restrict__ W3, float* __restrict__ H3a, int n) {
    __shared__ float Ws[32 * 16];
    __shared__ float rows[32][36];  // pad 36
    const int tid = threadIdx.x;
    for (int i = tid; i < 32 * 16; i += 256) Ws[i] = W3[i];
    const int t = blockIdx.x * 256 + tid;
    const int node = t >> 3, q = t & 7, nl = tid >> 3;
    float4 acc = make_float4(0.f, 0.f, 0.f, 0.f);
    int p0 = offs[node], p1 = offs[node + 1];
    for (int p = p0; p < p1; ++p) {
        float ww = w[p];
        float4 hv = *(const float4*)(h + (size_t)src[p] * 32 + q * 4);
        acc.x = fmaf(ww, hv.x, acc.x);
        acc.y = fmaf(ww, hv.y, acc.y);
        acc.z = fmaf(ww, hv.z, acc.z);
        acc.w = fmaf(ww, hv.w, acc.w);
    }
    float d = dis[node];
    float ds = d * d;
    float4 hv = *(const float4*)(h + (size_t)node * 32 + q * 4);
    float4 bv = *(const float4*)(b2 + q * 4);
    acc.x = fmaxf(fmaf(ds, hv.x, acc.x) + bv.x, 0.f);
    acc.y = fmaxf(fmaf(ds, hv.y, acc.y) + bv.y, 0.f);
    acc.z = fmaxf(fmaf(ds, hv.z, acc.z) + bv.z, 0.f);
    acc.w = fmaxf(fmaf(ds, hv.w, acc.w) + bv.w, 0.f);
    *(float4*)&rows[nl][q * 4] = acc;
    __syncthreads();
    const int c0 = q * 2;
    float s0 = 0.f, s1 = 0.f;
#pragma unroll
    for (int k = 0; k < 32; ++k) {
        float v = rows[nl][k];
        s0 = fmaf(v, Ws[k * 16 + c0], s0);
        s1 = fmaf(v, Ws[k * 16 + c0 + 1], s1);
    }
    H3a[(size_t)node * 16 + c0] = s0;
    H3a[(size_t)node * 16 + c0 + 1] = s1;
}

// --- final propagate (F=16) + bias + softmax, float4/thread, 4 lanes/node
__global__ void prop_softmax_k(const float* __restrict__ h, const int* __restrict__ offs,
                               const int* __restrict__ src, const float* __restrict__ w,
                               const float* __restrict__ dis, const float* __restrict__ b,
                               float* __restrict__ out, int n) {
    int t = blockIdx.x * blockDim.x + threadIdx.x;
    int node = t >> 2, q = t & 3;
    if (node >= n) return;
    float4 acc = make_float4(0.f, 0.f, 0.f, 0.f);
    int p0 = offs[node], p1 = offs[node + 1];
    for (int p = p0; p < p1; ++p) {
        float ww = w[p];
        float4 hv = *(const float4*)(h + (size_t)src[p] * 16 + q * 4);
        acc.x = fmaf(ww, hv.x, acc.x);
        acc.y = fmaf(ww, hv.y, acc.y);
        acc.z = fmaf(ww, hv.z, acc.z);
        acc.w = fmaf(ww, hv.w, acc.w);
    }
    float d = dis[node];
    float ds = d * d;
    float4 hv = *(const float4*)(h + (size_t)node * 16 + q * 4);
    float4 bv = *(const float4*)(b + q * 4);
    acc.x = fmaf(ds, hv.x, acc.x) + bv.x;
    acc.y = fmaf(ds, hv.y, acc.y) + bv.y;
    acc.z = fmaf(ds, hv.z, acc.z) + bv.z;
    acc.w = fmaf(ds, hv.w, acc.w) + bv.w;
    float m = fmaxf(fmaxf(acc.x, acc.y), fmaxf(acc.z, acc.w));
    m = fmaxf(m, __shfl_xor(m, 1));
    m = fmaxf(m, __shfl_xor(m, 2));
    float4 e;
    e.x = __expf(acc.x - m);
    e.y = __expf(acc.y - m);
    e.z = __expf(acc.z - m);
    e.w = __expf(acc.w - m);
    float s = e.x + e.y + e.z + e.w;
    s += __shfl_xor(s, 1);
    s += __shfl_xor(s, 2);
    float inv = 1.f / s;
    e.x *= inv; e.y *= inv; e.z *= inv; e.w *= inv;
    *(float4*)(out + (size_t)node * 16 + q * 4) = e;
}

extern "C" void kernel_launch(void* const* d_in, const int* in_sizes, int n_in,
                              void* d_out, int out_size, void* d_ws, size_t ws_size,
                              hipStream_t stream) {
    const float* x  = (const float*)d_in[0];
    const int*   ei = (const int*)d_in[1];
    const float* W1 = (const float*)d_in[2];
    const float* b1 = (const float*)d_in[3];
    const float* W2 = (const float*)d_in[4];
    const float* b2 = (const float*)d_in[5];
    const float* W3 = (const float*)d_in[6];
    const float* b3 = (const float*)d_in[7];
    float* out = (float*)d_out;

    const int n = in_sizes[2] / 64;
    const int K = in_sizes[0] / n;
    const int E = in_sizes[1] / 2;

    char* ws = (char*)d_ws;
    size_t off = 0;
    auto alloc = [&](size_t bytes) {
        char* p = ws + off;
        off = (off + bytes + 255) & ~(size_t)255;
        return p;
    };
    int*   flag   = (int*)  alloc(4);
    int*   cnt    = (int*)  alloc((size_t)n * 4);
    int*   cursor = (int*)  alloc((size_t)n * 4);
    int*   offs   = (int*)  alloc((size_t)(n + 1) * 4);
    float* dis    = (float*)alloc((size_t)n * 4);
    int*   csrs   = (int*)  alloc((size_t)E * 4);
    float* csrw   = (float*)alloc((size_t)E * 4);
    unsigned short* Btw = (unsigned short*)alloc((size_t)2 * 64 * K * 2);
    float* P      = (float*)alloc((size_t)4 * n * 64 * 4);  // partials; plane 0 = H0
    float* H2a    = (float*)alloc((size_t)n * 32 * 4);
    float* H3a    = (float*)alloc((size_t)n * 16 * 4);
    (void)ws_size; (void)n_in; (void)out_size;

    init_prep_k<<<(K * 64 + 255) / 256, 256, 0, stream>>>(ei, flag, cnt, n, W1, Btw, K);
    count_deg_k<<<(E + 255) / 256, 256, 0, stream>>>(ei, E, flag, cnt);
    scan_k<<<1, 1024, 0, stream>>>(cnt, offs, dis, cursor, n);
    fill_csr_k<<<(E + 255) / 256, 256, 0, stream>>>(ei, E, flag, offs, cursor, dis, csrs, csrw);

    gemm1_mfma_k<<<(n / 128) * 4, 256, 0, stream>>>(x, Btw, P, n, K, K / 4);
    size_t q = (size_t)n * 64 / 4;
    reduce4_k<<<(int)((q + 255) / 256), 256, 0, stream>>>((float4*)P, q);

    prop64_gemm2_k<<<n * 16 / 256, 256, 0, stream>>>(P, offs, csrs, csrw, dis, b1, W2, H2a, n);
    prop32_gemm3_k<<<n * 8 / 256, 256, 0, stream>>>(H2a, offs, csrs, csrw, dis, b2, W3, H3a, n);
    prop_softmax_k<<<n * 4 / 256, 256, 0, stream>>>(H3a, offs, csrs, csrw, dis, b3, out, n);
}